// Round 1
// baseline (1632.112 us; speedup 1.0000x reference)
//
#include <hip/hip_runtime.h>
#include <hip/hip_bf16.h>
#include <math.h>

// ---------------- GEMM: z = h @ W^T + b  (fp32, N x 128, K=128) -------------
// block: 32 nodes x 64 outs (grid.y selects which 64-out half), 256 threads.
__global__ __launch_bounds__(256) void k_gemm(const float* __restrict__ h,
                                              const float* __restrict__ W,
                                              const float* __restrict__ bias,
                                              float* __restrict__ z, int N) {
    __shared__ float Wt[128][64];    // Wt[k][o_local], 32 KB
    __shared__ float hl[32][132];    // padded, 16.9 KB
    const int t = threadIdx.x;
    const int obase = blockIdx.y * 64;
    const int n0 = blockIdx.x * 32;

    // stage W transposed: 64 rows x 128 k = 2048 float4, 8 per thread
    for (int i = 0; i < 8; ++i) {
        int f = i * 256 + t;
        int ol = f >> 5, k4 = (f & 31) * 4;
        float4 w = *reinterpret_cast<const float4*>(&W[(size_t)(obase + ol) * 128 + k4]);
        Wt[k4 + 0][ol] = w.x; Wt[k4 + 1][ol] = w.y;
        Wt[k4 + 2][ol] = w.z; Wt[k4 + 3][ol] = w.w;
    }
    // stage h tile: 32 rows x 128 = 1024 float4, 4 per thread
    for (int i = 0; i < 4; ++i) {
        int f = i * 256 + t;
        int r = f >> 5, k4 = (f & 31) * 4;
        int node = n0 + r;
        float4 v = make_float4(0.f, 0.f, 0.f, 0.f);
        if (node < N) v = *reinterpret_cast<const float4*>(&h[(size_t)node * 128 + k4]);
        *reinterpret_cast<float4*>(&hl[r][k4]) = v;
    }
    __syncthreads();

    const int og = t & 15;   // outs og*4 .. og*4+3
    const int ng = t >> 4;   // nodes ng*2, ng*2+1
    const int o0 = og * 4;
    const int nA = ng * 2, nB = nA + 1;
    float4 acc0 = make_float4(0.f, 0.f, 0.f, 0.f);
    float4 acc1 = make_float4(0.f, 0.f, 0.f, 0.f);
#pragma unroll 8
    for (int k = 0; k < 128; ++k) {
        float4 w = *reinterpret_cast<const float4*>(&Wt[k][o0]);
        float a = hl[nA][k], b = hl[nB][k];
        acc0.x += w.x * a; acc0.y += w.y * a; acc0.z += w.z * a; acc0.w += w.w * a;
        acc1.x += w.x * b; acc1.y += w.y * b; acc1.z += w.z * b; acc1.w += w.w * b;
    }
    float4 bs = *reinterpret_cast<const float4*>(&bias[obase + o0]);
    int nodeA = n0 + nA, nodeB = n0 + nB;
    if (nodeA < N) {
        float4 r = make_float4(acc0.x + bs.x, acc0.y + bs.y, acc0.z + bs.z, acc0.w + bs.w);
        *reinterpret_cast<float4*>(&z[(size_t)nodeA * 128 + obase + o0]) = r;
    }
    if (nodeB < N) {
        float4 r = make_float4(acc1.x + bs.x, acc1.y + bs.y, acc1.z + bs.z, acc1.w + bs.w);
        *reinterpret_cast<float4*>(&z[(size_t)nodeB * 128 + obase + o0]) = r;
    }
}

// ------------- per-node score halves: s_src[n,h], s_dst[n,h] ----------------
__global__ __launch_bounds__(256) void k_scores(const float* __restrict__ z,
                                                const float* __restrict__ att,
                                                float* __restrict__ s_src,
                                                float* __restrict__ s_dst, int N) {
    int gid = blockIdx.x * 256 + threadIdx.x;
    if (gid >= N * 4) return;
    int n = gid >> 2, hd = gid & 3;
    const float* zp = z + (size_t)n * 128 + hd * 32;
    const float* as = att + hd * 65;
    float ss = 0.f, sd = 0.f;
#pragma unroll
    for (int i = 0; i < 32; i += 4) {
        float4 v = *reinterpret_cast<const float4*>(zp + i);
        ss += v.x * as[i] + v.y * as[i + 1] + v.z * as[i + 2] + v.w * as[i + 3];
        sd += v.x * as[32 + i] + v.y * as[32 + i + 1] + v.z * as[32 + i + 2] + v.w * as[32 + i + 3];
    }
    s_src[gid] = ss;
    s_dst[gid] = sd;
}

// ------------- edge pass A: alpha = exp(clip(leaky(score))), denom ----------
__global__ __launch_bounds__(256) void k_edge_a(const int* __restrict__ src,
                                                const int* __restrict__ dst,
                                                const float* __restrict__ ef,
                                                const float* __restrict__ att,
                                                const float* __restrict__ s_src,
                                                const float* __restrict__ s_dst,
                                                float* __restrict__ alpha,
                                                float* __restrict__ denom, int E) {
    int e = blockIdx.x * 256 + threadIdx.x;
    if (e >= E) return;
    int s = src[e], d = dst[e];
    float f = ef[e];
    float4 ss = *reinterpret_cast<const float4*>(&s_src[(size_t)s * 4]);
    float4 sd = *reinterpret_cast<const float4*>(&s_dst[(size_t)d * 4]);
    const float* ssp = reinterpret_cast<const float*>(&ss);
    const float* sdp = reinterpret_cast<const float*>(&sd);
    float a[4];
#pragma unroll
    for (int hd = 0; hd < 4; ++hd) {
        float sc = ssp[hd] + sdp[hd] + f * att[hd * 65 + 64];
        sc = sc >= 0.f ? sc : 0.2f * sc;
        sc = fminf(fmaxf(sc, -20.f), 20.f);
        a[hd] = expf(sc);
        atomicAdd(&denom[(size_t)d * 4 + hd], a[hd]);
    }
    *reinterpret_cast<float4*>(&alpha[(size_t)e * 4]) = make_float4(a[0], a[1], a[2], a[3]);
}

// ------------- edge pass B: outagg[dst] += z[src] * alpha/denom -------------
// 32 threads per edge, 4 channels each (float4), 8 edges per 256-block.
__global__ __launch_bounds__(256) void k_edge_b(const int* __restrict__ src,
                                                const int* __restrict__ dst,
                                                const float* __restrict__ alpha,
                                                const float* __restrict__ denom,
                                                const float* __restrict__ z,
                                                float* __restrict__ outagg, int E) {
    int t = threadIdx.x;
    int e = blockIdx.x * 8 + (t >> 5);
    if (e >= E) return;
    int lane = t & 31;
    int c = lane * 4;          // channel base 0..124
    int hd = c >> 5;           // head 0..3
    int s = src[e], d = dst[e];
    float w = alpha[(size_t)e * 4 + hd] / (denom[(size_t)d * 4 + hd] + 1e-6f);
    float4 zv = *reinterpret_cast<const float4*>(&z[(size_t)s * 128 + c]);
    float* op = &outagg[(size_t)d * 128 + c];
    atomicAdd(op + 0, zv.x * w);
    atomicAdd(op + 1, zv.y * w);
    atomicAdd(op + 2, zv.z * w);
    atomicAdd(op + 3, zv.w * w);
}

// ------------- finalize: residual + LayerNorm + ELU -------------------------
// one 64-lane wave per node, 2 channels per lane; 4 nodes per 256-block.
__global__ __launch_bounds__(256) void k_final(const float* __restrict__ outagg,
                                               const float* __restrict__ z,
                                               const float* __restrict__ g,
                                               const float* __restrict__ b,
                                               float* __restrict__ out, int N) {
    int wave = threadIdx.x >> 6, lane = threadIdx.x & 63;
    int n = blockIdx.x * 4 + wave;
    if (n >= N) return;
    float2 v = *reinterpret_cast<const float2*>(&outagg[(size_t)n * 128 + lane * 2]);
    float2 zv = *reinterpret_cast<const float2*>(&z[(size_t)n * 128 + lane * 2]);
    float x0 = v.x + zv.x, x1 = v.y + zv.y;
    float s = x0 + x1;
    for (int off = 32; off; off >>= 1) s += __shfl_xor(s, off);
    float mu = s * (1.f / 128.f);
    float d0 = x0 - mu, d1 = x1 - mu;
    float q = d0 * d0 + d1 * d1;
    for (int off = 32; off; off >>= 1) q += __shfl_xor(q, off);
    float rstd = rsqrtf(q * (1.f / 128.f) + 1e-5f);
    float2 gg = *reinterpret_cast<const float2*>(&g[lane * 2]);
    float2 bb = *reinterpret_cast<const float2*>(&b[lane * 2]);
    float y0 = d0 * rstd * gg.x + bb.x;
    float y1 = d1 * rstd * gg.y + bb.y;
    y0 = y0 > 0.f ? y0 : expf(y0) - 1.f;
    y1 = y1 > 0.f ? y1 : expf(y1) - 1.f;
    *reinterpret_cast<float2*>(&out[(size_t)n * 128 + lane * 2]) = make_float2(y0, y1);
}

extern "C" void kernel_launch(void* const* d_in, const int* in_sizes, int n_in,
                              void* d_out, int out_size, void* d_ws, size_t ws_size,
                              hipStream_t stream) {
    const float* h   = (const float*)d_in[0];
    const int*   ei  = (const int*)d_in[1];
    const float* ef  = (const float*)d_in[2];
    const float* Ww  = (const float*)d_in[3];
    const float* Wb  = (const float*)d_in[4];
    const float* att = (const float*)d_in[5];
    const float* lng = (const float*)d_in[6];
    const float* lnb = (const float*)d_in[7];
    float* out = (float*)d_out;

    const int N = in_sizes[0] / 128;   // 50000
    const int E = in_sizes[1] / 2;     // 800000
    const int* src = ei;
    const int* dst = ei + E;

    char* ws = (char*)d_ws;
    float* z      = (float*)ws; ws += (size_t)N * 128 * 4;
    float* s_src  = (float*)ws; ws += (size_t)N * 4 * 4;
    float* s_dst  = (float*)ws; ws += (size_t)N * 4 * 4;
    float* denom  = (float*)ws; ws += (size_t)N * 4 * 4;
    float* alpha  = (float*)ws; ws += (size_t)E * 4 * 4;
    float* outagg = (float*)ws; ws += (size_t)N * 128 * 4;

    hipMemsetAsync(denom, 0, (size_t)N * 4 * 4, stream);
    hipMemsetAsync(outagg, 0, (size_t)N * 128 * 4, stream);

    dim3 gGemm((N + 31) / 32, 2);
    k_gemm<<<gGemm, 256, 0, stream>>>(h, Ww, Wb, z, N);
    k_scores<<<(N * 4 + 255) / 256, 256, 0, stream>>>(z, att, s_src, s_dst, N);
    k_edge_a<<<(E + 255) / 256, 256, 0, stream>>>(src, dst, ef, att, s_src, s_dst, alpha, denom, E);
    k_edge_b<<<(E + 7) / 8, 256, 0, stream>>>(src, dst, alpha, denom, z, outagg, E);
    k_final<<<(N + 3) / 4, 256, 0, stream>>>(outagg, z, lng, lnb, out, N);
}

// Round 2
// 416.889 us; speedup vs baseline: 3.9150x; 3.9150x over previous
//
#include <hip/hip_runtime.h>
#include <hip/hip_bf16.h>
#include <math.h>

#define CHUNK 1024

// ---------------- GEMM: z = h @ W^T + b  (fp32, N x 128, K=128) -------------
__global__ __launch_bounds__(256) void k_gemm(const float* __restrict__ h,
                                              const float* __restrict__ W,
                                              const float* __restrict__ bias,
                                              float* __restrict__ z, int N) {
    __shared__ float Wt[128][64];
    __shared__ float hl[32][132];
    const int t = threadIdx.x;
    const int obase = blockIdx.y * 64;
    const int n0 = blockIdx.x * 32;

    for (int i = 0; i < 8; ++i) {
        int f = i * 256 + t;
        int ol = f >> 5, k4 = (f & 31) * 4;
        float4 w = *reinterpret_cast<const float4*>(&W[(size_t)(obase + ol) * 128 + k4]);
        Wt[k4 + 0][ol] = w.x; Wt[k4 + 1][ol] = w.y;
        Wt[k4 + 2][ol] = w.z; Wt[k4 + 3][ol] = w.w;
    }
    for (int i = 0; i < 4; ++i) {
        int f = i * 256 + t;
        int r = f >> 5, k4 = (f & 31) * 4;
        int node = n0 + r;
        float4 v = make_float4(0.f, 0.f, 0.f, 0.f);
        if (node < N) v = *reinterpret_cast<const float4*>(&h[(size_t)node * 128 + k4]);
        *reinterpret_cast<float4*>(&hl[r][k4]) = v;
    }
    __syncthreads();

    const int og = t & 15;
    const int ng = t >> 4;
    const int o0 = og * 4;
    const int nA = ng * 2, nB = nA + 1;
    float4 acc0 = make_float4(0.f, 0.f, 0.f, 0.f);
    float4 acc1 = make_float4(0.f, 0.f, 0.f, 0.f);
#pragma unroll 8
    for (int k = 0; k < 128; ++k) {
        float4 w = *reinterpret_cast<const float4*>(&Wt[k][o0]);
        float a = hl[nA][k], b = hl[nB][k];
        acc0.x += w.x * a; acc0.y += w.y * a; acc0.z += w.z * a; acc0.w += w.w * a;
        acc1.x += w.x * b; acc1.y += w.y * b; acc1.z += w.z * b; acc1.w += w.w * b;
    }
    float4 bs = *reinterpret_cast<const float4*>(&bias[obase + o0]);
    int nodeA = n0 + nA, nodeB = n0 + nB;
    if (nodeA < N) {
        float4 r = make_float4(acc0.x + bs.x, acc0.y + bs.y, acc0.z + bs.z, acc0.w + bs.w);
        *reinterpret_cast<float4*>(&z[(size_t)nodeA * 128 + obase + o0]) = r;
    }
    if (nodeB < N) {
        float4 r = make_float4(acc1.x + bs.x, acc1.y + bs.y, acc1.z + bs.z, acc1.w + bs.w);
        *reinterpret_cast<float4*>(&z[(size_t)nodeB * 128 + obase + o0]) = r;
    }
}

// ------------- per-node score halves ----------------------------------------
__global__ __launch_bounds__(256) void k_scores(const float* __restrict__ z,
                                                const float* __restrict__ att,
                                                float* __restrict__ s_src,
                                                float* __restrict__ s_dst, int N) {
    int gid = blockIdx.x * 256 + threadIdx.x;
    if (gid >= N * 4) return;
    int n = gid >> 2, hd = gid & 3;
    const float* zp = z + (size_t)n * 128 + hd * 32;
    const float* as = att + hd * 65;
    float ss = 0.f, sd = 0.f;
#pragma unroll
    for (int i = 0; i < 32; i += 4) {
        float4 v = *reinterpret_cast<const float4*>(zp + i);
        ss += v.x * as[i] + v.y * as[i + 1] + v.z * as[i + 2] + v.w * as[i + 3];
        sd += v.x * as[32 + i] + v.y * as[32 + i + 1] + v.z * as[32 + i + 2] + v.w * as[32 + i + 3];
    }
    s_src[gid] = ss;
    s_dst[gid] = sd;
}

// ------------- edge pass A: alpha + denom (float atomics, 3.2M) -------------
__global__ __launch_bounds__(256) void k_edge_a(const int* __restrict__ src,
                                                const int* __restrict__ dst,
                                                const float* __restrict__ ef,
                                                const float* __restrict__ att,
                                                const float* __restrict__ s_src,
                                                const float* __restrict__ s_dst,
                                                float* __restrict__ alpha,
                                                float* __restrict__ denom, int E) {
    int e = blockIdx.x * 256 + threadIdx.x;
    if (e >= E) return;
    int s = src[e], d = dst[e];
    float f = ef[e];
    float4 ss = *reinterpret_cast<const float4*>(&s_src[(size_t)s * 4]);
    float4 sd = *reinterpret_cast<const float4*>(&s_dst[(size_t)d * 4]);
    const float* ssp = reinterpret_cast<const float*>(&ss);
    const float* sdp = reinterpret_cast<const float*>(&sd);
    float a[4];
#pragma unroll
    for (int hd = 0; hd < 4; ++hd) {
        float sc = ssp[hd] + sdp[hd] + f * att[hd * 65 + 64];
        sc = sc >= 0.f ? sc : 0.2f * sc;
        sc = fminf(fmaxf(sc, -20.f), 20.f);
        a[hd] = expf(sc);
        atomicAdd(&denom[(size_t)d * 4 + hd], a[hd]);
    }
    *reinterpret_cast<float4*>(&alpha[(size_t)e * 4]) = make_float4(a[0], a[1], a[2], a[3]);
}

// ------------- CSR build: histogram -----------------------------------------
__global__ __launch_bounds__(256) void k_hist(const int* __restrict__ dst,
                                              int* __restrict__ counts, int E) {
    int e = blockIdx.x * 256 + threadIdx.x;
    if (e < E) atomicAdd(&counts[dst[e]], 1);
}

// per-chunk exclusive scan (CHUNK=1024, 256 thr x 4 items) + block totals
__global__ __launch_bounds__(256) void k_scan_block(const int* __restrict__ counts,
                                                    int* __restrict__ offs,
                                                    int* __restrict__ bsum, int N) {
    __shared__ int sd[256];
    int t = threadIdx.x, b = blockIdx.x;
    int i0 = b * CHUNK + t * 4;
    int c[4];
#pragma unroll
    for (int j = 0; j < 4; ++j) c[j] = (i0 + j < N) ? counts[i0 + j] : 0;
    int tsum = c[0] + c[1] + c[2] + c[3];
    sd[t] = tsum;
    __syncthreads();
    for (int d = 1; d < 256; d <<= 1) {
        int v = (t >= d) ? sd[t - d] : 0;
        __syncthreads();
        sd[t] += v;
        __syncthreads();
    }
    int pre = sd[t] - tsum;   // exclusive within chunk
#pragma unroll
    for (int j = 0; j < 4; ++j) {
        if (i0 + j < N) offs[i0 + j] = pre;
        pre += c[j];
    }
    if (t == 255) bsum[b] = sd[255];
}

// single-wave exclusive scan of block sums (nb <= 64)
__global__ void k_scan_top(const int* __restrict__ bsum, int* __restrict__ bscan, int nb) {
    int lane = threadIdx.x & 63;
    int x = (lane < nb) ? bsum[lane] : 0;
    int own = x;
    for (int d = 1; d < 64; d <<= 1) {
        int v = __shfl_up(x, d);
        if (lane >= d) x += v;
    }
    if (lane < nb) bscan[lane] = x - own;
}

__global__ __launch_bounds__(256) void k_addoff(int* __restrict__ offs,
                                                int* __restrict__ cursor,
                                                const int* __restrict__ bscan, int N) {
    int i = blockIdx.x * 256 + threadIdx.x;
    if (i < N) {
        int o = offs[i] + bscan[i >> 10];
        offs[i] = o;
        cursor[i] = o;
    }
}

// ------------- scatter edges into dst buckets; precompute weights -----------
__global__ __launch_bounds__(256) void k_scatter(const int* __restrict__ src,
                                                 const int* __restrict__ dst,
                                                 const float* __restrict__ alpha,
                                                 const float* __restrict__ denom,
                                                 int* __restrict__ cursor,
                                                 int* __restrict__ s_sorted,
                                                 float* __restrict__ w_sorted, int E) {
    int e = blockIdx.x * 256 + threadIdx.x;
    if (e >= E) return;
    int d = dst[e];
    int pos = atomicAdd(&cursor[d], 1);
    float4 a  = *reinterpret_cast<const float4*>(&alpha[(size_t)e * 4]);
    float4 dn = *reinterpret_cast<const float4*>(&denom[(size_t)d * 4]);
    float4 w = make_float4(a.x / (dn.x + 1e-6f), a.y / (dn.y + 1e-6f),
                           a.z / (dn.z + 1e-6f), a.w / (dn.w + 1e-6f));
    s_sorted[pos] = src[e];
    *reinterpret_cast<float4*>(&w_sorted[(size_t)pos * 4]) = w;
}

// ------------- aggregate per node + residual + LN + ELU (fused) -------------
// one 64-lane wave per node; lane owns channels [2*lane, 2*lane+1]
__global__ __launch_bounds__(256) void k_agg_final(const int* __restrict__ offs,
                                                   const int* __restrict__ counts,
                                                   const int* __restrict__ s_sorted,
                                                   const float* __restrict__ w_sorted,
                                                   const float* __restrict__ z,
                                                   const float* __restrict__ g,
                                                   const float* __restrict__ bparm,
                                                   float* __restrict__ out, int N) {
    int wave = threadIdx.x >> 6, lane = threadIdx.x & 63;
    int n = blockIdx.x * 4 + wave;
    if (n >= N) return;
    int start = offs[n], len = counts[n];
    int hd = lane >> 4;        // head for channel 2*lane
    int c = lane * 2;
    float ax = 0.f, ay = 0.f, bx = 0.f, by = 0.f;
    int i = start, end = start + len;
    for (; i + 1 < end; i += 2) {
        int s0 = s_sorted[i], s1 = s_sorted[i + 1];
        float w0 = w_sorted[(size_t)i * 4 + hd];
        float w1 = w_sorted[(size_t)(i + 1) * 4 + hd];
        float2 z0 = *reinterpret_cast<const float2*>(&z[(size_t)s0 * 128 + c]);
        float2 z1 = *reinterpret_cast<const float2*>(&z[(size_t)s1 * 128 + c]);
        ax += z0.x * w0; ay += z0.y * w0;
        bx += z1.x * w1; by += z1.y * w1;
    }
    if (i < end) {
        int s0 = s_sorted[i];
        float w0 = w_sorted[(size_t)i * 4 + hd];
        float2 z0 = *reinterpret_cast<const float2*>(&z[(size_t)s0 * 128 + c]);
        ax += z0.x * w0; ay += z0.y * w0;
    }
    float2 zv = *reinterpret_cast<const float2*>(&z[(size_t)n * 128 + c]);
    float x0 = ax + bx + zv.x;
    float x1 = ay + by + zv.y;
    float s = x0 + x1;
    for (int off = 32; off; off >>= 1) s += __shfl_xor(s, off);
    float mu = s * (1.f / 128.f);
    float d0 = x0 - mu, d1 = x1 - mu;
    float q = d0 * d0 + d1 * d1;
    for (int off = 32; off; off >>= 1) q += __shfl_xor(q, off);
    float rstd = rsqrtf(q * (1.f / 128.f) + 1e-5f);
    float2 gg = *reinterpret_cast<const float2*>(&g[c]);
    float2 bb = *reinterpret_cast<const float2*>(&bparm[c]);
    float y0 = d0 * rstd * gg.x + bb.x;
    float y1 = d1 * rstd * gg.y + bb.y;
    y0 = y0 > 0.f ? y0 : expf(y0) - 1.f;
    y1 = y1 > 0.f ? y1 : expf(y1) - 1.f;
    *reinterpret_cast<float2*>(&out[(size_t)n * 128 + c]) = make_float2(y0, y1);
}

extern "C" void kernel_launch(void* const* d_in, const int* in_sizes, int n_in,
                              void* d_out, int out_size, void* d_ws, size_t ws_size,
                              hipStream_t stream) {
    const float* h   = (const float*)d_in[0];
    const int*   ei  = (const int*)d_in[1];
    const float* ef  = (const float*)d_in[2];
    const float* Ww  = (const float*)d_in[3];
    const float* Wb  = (const float*)d_in[4];
    const float* att = (const float*)d_in[5];
    const float* lng = (const float*)d_in[6];
    const float* lnb = (const float*)d_in[7];
    float* out = (float*)d_out;

    const int N = in_sizes[0] / 128;   // 50000
    const int E = in_sizes[1] / 2;     // 800000
    const int* src = ei;
    const int* dst = ei + E;
    const int nb = (N + CHUNK - 1) / CHUNK;   // 49 (<=64 required)

    char* ws = (char*)d_ws;
    float* z        = (float*)ws; ws += (size_t)N * 128 * 4;
    float* s_src    = (float*)ws; ws += (size_t)N * 4 * 4;
    float* s_dst    = (float*)ws; ws += (size_t)N * 4 * 4;
    float* denom    = (float*)ws; ws += (size_t)N * 4 * 4;
    float* alpha    = (float*)ws; ws += (size_t)E * 4 * 4;
    int*   counts   = (int*)ws;   ws += (size_t)N * 4;
    int*   offs     = (int*)ws;   ws += (size_t)N * 4;
    int*   cursor   = (int*)ws;   ws += (size_t)N * 4;
    int*   bsum     = (int*)ws;   ws += (size_t)64 * 4;
    int*   bscan    = (int*)ws;   ws += (size_t)64 * 4;
    int*   s_sorted = (int*)ws;   ws += (size_t)E * 4;
    float* w_sorted = (float*)ws; ws += (size_t)E * 4 * 4;

    hipMemsetAsync(denom, 0, (size_t)N * 4 * 4, stream);
    hipMemsetAsync(counts, 0, (size_t)N * 4, stream);

    dim3 gGemm((N + 31) / 32, 2);
    k_gemm<<<gGemm, 256, 0, stream>>>(h, Ww, Wb, z, N);
    k_hist<<<(E + 255) / 256, 256, 0, stream>>>(dst, counts, E);
    k_scores<<<(N * 4 + 255) / 256, 256, 0, stream>>>(z, att, s_src, s_dst, N);
    k_edge_a<<<(E + 255) / 256, 256, 0, stream>>>(src, dst, ef, att, s_src, s_dst, alpha, denom, E);
    k_scan_block<<<nb, 256, 0, stream>>>(counts, offs, bsum, N);
    k_scan_top<<<1, 64, 0, stream>>>(bsum, bscan, nb);
    k_addoff<<<(N + 255) / 256, 256, 0, stream>>>(offs, cursor, bscan, N);
    k_scatter<<<(E + 255) / 256, 256, 0, stream>>>(src, dst, alpha, denom, cursor, s_sorted, w_sorted, E);
    k_agg_final<<<(N + 3) / 4, 256, 0, stream>>>(offs, counts, s_sorted, w_sorted, z, lng, lnb, out, N);
}

// Round 3
// 256.904 us; speedup vs baseline: 6.3530x; 1.6227x over previous
//
#include <hip/hip_runtime.h>
#include <hip/hip_bf16.h>
#include <math.h>

#define CHUNK 1024

// ---------------- GEMM: z = h @ W^T + b  (fp32, N x 128, K=128) -------------
__global__ __launch_bounds__(256) void k_gemm(const float* __restrict__ h,
                                              const float* __restrict__ W,
                                              const float* __restrict__ bias,
                                              float* __restrict__ z, int N) {
    __shared__ float Wt[128][64];
    __shared__ float hl[32][132];
    const int t = threadIdx.x;
    const int obase = blockIdx.y * 64;
    const int n0 = blockIdx.x * 32;

    for (int i = 0; i < 8; ++i) {
        int f = i * 256 + t;
        int ol = f >> 5, k4 = (f & 31) * 4;
        float4 w = *reinterpret_cast<const float4*>(&W[(size_t)(obase + ol) * 128 + k4]);
        Wt[k4 + 0][ol] = w.x; Wt[k4 + 1][ol] = w.y;
        Wt[k4 + 2][ol] = w.z; Wt[k4 + 3][ol] = w.w;
    }
    for (int i = 0; i < 4; ++i) {
        int f = i * 256 + t;
        int r = f >> 5, k4 = (f & 31) * 4;
        int node = n0 + r;
        float4 v = make_float4(0.f, 0.f, 0.f, 0.f);
        if (node < N) v = *reinterpret_cast<const float4*>(&h[(size_t)node * 128 + k4]);
        *reinterpret_cast<float4*>(&hl[r][k4]) = v;
    }
    __syncthreads();

    const int og = t & 15;
    const int ng = t >> 4;
    const int o0 = og * 4;
    const int nA = ng * 2, nB = nA + 1;
    float4 acc0 = make_float4(0.f, 0.f, 0.f, 0.f);
    float4 acc1 = make_float4(0.f, 0.f, 0.f, 0.f);
#pragma unroll 8
    for (int k = 0; k < 128; ++k) {
        float4 w = *reinterpret_cast<const float4*>(&Wt[k][o0]);
        float a = hl[nA][k], b = hl[nB][k];
        acc0.x += w.x * a; acc0.y += w.y * a; acc0.z += w.z * a; acc0.w += w.w * a;
        acc1.x += w.x * b; acc1.y += w.y * b; acc1.z += w.z * b; acc1.w += w.w * b;
    }
    float4 bs = *reinterpret_cast<const float4*>(&bias[obase + o0]);
    int nodeA = n0 + nA, nodeB = n0 + nB;
    if (nodeA < N) {
        float4 r = make_float4(acc0.x + bs.x, acc0.y + bs.y, acc0.z + bs.z, acc0.w + bs.w);
        *reinterpret_cast<float4*>(&z[(size_t)nodeA * 128 + obase + o0]) = r;
    }
    if (nodeB < N) {
        float4 r = make_float4(acc1.x + bs.x, acc1.y + bs.y, acc1.z + bs.z, acc1.w + bs.w);
        *reinterpret_cast<float4*>(&z[(size_t)nodeB * 128 + obase + o0]) = r;
    }
}

// ------------- per-node score halves ----------------------------------------
__global__ __launch_bounds__(256) void k_scores(const float* __restrict__ z,
                                                const float* __restrict__ att,
                                                float* __restrict__ s_src,
                                                float* __restrict__ s_dst, int N) {
    int gid = blockIdx.x * 256 + threadIdx.x;
    if (gid >= N * 4) return;
    int n = gid >> 2, hd = gid & 3;
    const float* zp = z + (size_t)n * 128 + hd * 32;
    const float* as = att + hd * 65;
    float ss = 0.f, sd = 0.f;
#pragma unroll
    for (int i = 0; i < 32; i += 4) {
        float4 v = *reinterpret_cast<const float4*>(zp + i);
        ss += v.x * as[i] + v.y * as[i + 1] + v.z * as[i + 2] + v.w * as[i + 3];
        sd += v.x * as[32 + i] + v.y * as[32 + i + 1] + v.z * as[32 + i + 2] + v.w * as[32 + i + 3];
    }
    s_src[gid] = ss;
    s_dst[gid] = sd;
}

// ------------- CSR build: histogram -----------------------------------------
__global__ __launch_bounds__(256) void k_hist(const int* __restrict__ dst,
                                              int* __restrict__ counts, int E) {
    int e = blockIdx.x * 256 + threadIdx.x;
    if (e < E) atomicAdd(&counts[dst[e]], 1);
}

// per-chunk exclusive scan (CHUNK=1024, 256 thr x 4 items) + block totals
__global__ __launch_bounds__(256) void k_scan_block(const int* __restrict__ counts,
                                                    int* __restrict__ offs,
                                                    int* __restrict__ bsum, int N) {
    __shared__ int sd[256];
    int t = threadIdx.x, b = blockIdx.x;
    int i0 = b * CHUNK + t * 4;
    int c[4];
#pragma unroll
    for (int j = 0; j < 4; ++j) c[j] = (i0 + j < N) ? counts[i0 + j] : 0;
    int tsum = c[0] + c[1] + c[2] + c[3];
    sd[t] = tsum;
    __syncthreads();
    for (int d = 1; d < 256; d <<= 1) {
        int v = (t >= d) ? sd[t - d] : 0;
        __syncthreads();
        sd[t] += v;
        __syncthreads();
    }
    int pre = sd[t] - tsum;
#pragma unroll
    for (int j = 0; j < 4; ++j) {
        if (i0 + j < N) offs[i0 + j] = pre;
        pre += c[j];
    }
    if (t == 255) bsum[b] = sd[255];
}

// single-wave exclusive scan of block sums (nb <= 64)
__global__ void k_scan_top(const int* __restrict__ bsum, int* __restrict__ bscan, int nb) {
    int lane = threadIdx.x & 63;
    int x = (lane < nb) ? bsum[lane] : 0;
    int own = x;
    for (int d = 1; d < 64; d <<= 1) {
        int v = __shfl_up(x, d);
        if (lane >= d) x += v;
    }
    if (lane < nb) bscan[lane] = x - own;
}

__global__ __launch_bounds__(256) void k_addoff(int* __restrict__ offs,
                                                int* __restrict__ cursor,
                                                const int* __restrict__ bscan, int N) {
    int i = blockIdx.x * 256 + threadIdx.x;
    if (i < N) {
        int o = offs[i] + bscan[i >> 10];
        offs[i] = o;
        cursor[i] = o;
    }
}

// ------------- scatter edges into dst buckets (packed {src, ef}) ------------
__global__ __launch_bounds__(256) void k_scatter(const int* __restrict__ src,
                                                 const int* __restrict__ dst,
                                                 const float* __restrict__ ef,
                                                 int* __restrict__ cursor,
                                                 int2* __restrict__ es, int E) {
    int e = blockIdx.x * 256 + threadIdx.x;
    if (e >= E) return;
    int d = dst[e];
    int pos = atomicAdd(&cursor[d], 1);
    es[pos] = make_int2(src[e], __float_as_int(ef[e]));
}

// ------------- fused: alpha + aggregate + residual + LN + ELU ---------------
// one 64-lane wave per node; lane owns channels [2*lane, 2*lane+1]
__global__ __launch_bounds__(256) void k_agg_final(const int* __restrict__ offs,
                                                   const int* __restrict__ counts,
                                                   const int2* __restrict__ es,
                                                   const float* __restrict__ s_src,
                                                   const float* __restrict__ s_dst,
                                                   const float* __restrict__ att,
                                                   const float* __restrict__ z,
                                                   const float* __restrict__ g,
                                                   const float* __restrict__ bparm,
                                                   float* __restrict__ out, int N) {
    int wave = threadIdx.x >> 6, lane = threadIdx.x & 63;
    int n = blockIdx.x * 4 + wave;
    if (n >= N) return;
    const int start = offs[n], len = counts[n];
    const int hd = lane >> 4;
    const int c = lane * 2;
    const float sdn = s_dst[(size_t)n * 4 + hd];
    const float attE = att[hd * 65 + 64];

    float ax = 0.f, ay = 0.f, da = 0.f;
    float bx = 0.f, by = 0.f, db = 0.f;
    int i = start;
    const int end = start + len;

    for (; i + 3 < end; i += 4) {
        int2 e0 = es[i], e1 = es[i + 1], e2 = es[i + 2], e3 = es[i + 3];
        float sc0 = s_src[(size_t)e0.x * 4 + hd] + sdn + __int_as_float(e0.y) * attE;
        float sc1 = s_src[(size_t)e1.x * 4 + hd] + sdn + __int_as_float(e1.y) * attE;
        float sc2 = s_src[(size_t)e2.x * 4 + hd] + sdn + __int_as_float(e2.y) * attE;
        float sc3 = s_src[(size_t)e3.x * 4 + hd] + sdn + __int_as_float(e3.y) * attE;
        sc0 = sc0 >= 0.f ? sc0 : 0.2f * sc0;
        sc1 = sc1 >= 0.f ? sc1 : 0.2f * sc1;
        sc2 = sc2 >= 0.f ? sc2 : 0.2f * sc2;
        sc3 = sc3 >= 0.f ? sc3 : 0.2f * sc3;
        float a0 = expf(fminf(fmaxf(sc0, -20.f), 20.f));
        float a1 = expf(fminf(fmaxf(sc1, -20.f), 20.f));
        float a2 = expf(fminf(fmaxf(sc2, -20.f), 20.f));
        float a3 = expf(fminf(fmaxf(sc3, -20.f), 20.f));
        float2 z0 = *reinterpret_cast<const float2*>(&z[(size_t)e0.x * 128 + c]);
        float2 z1 = *reinterpret_cast<const float2*>(&z[(size_t)e1.x * 128 + c]);
        float2 z2 = *reinterpret_cast<const float2*>(&z[(size_t)e2.x * 128 + c]);
        float2 z3 = *reinterpret_cast<const float2*>(&z[(size_t)e3.x * 128 + c]);
        ax += z0.x * a0; ay += z0.y * a0; da += a0;
        bx += z1.x * a1; by += z1.y * a1; db += a1;
        ax += z2.x * a2; ay += z2.y * a2; da += a2;
        bx += z3.x * a3; by += z3.y * a3; db += a3;
    }
    for (; i < end; ++i) {
        int2 e0 = es[i];
        float sc0 = s_src[(size_t)e0.x * 4 + hd] + sdn + __int_as_float(e0.y) * attE;
        sc0 = sc0 >= 0.f ? sc0 : 0.2f * sc0;
        float a0 = expf(fminf(fmaxf(sc0, -20.f), 20.f));
        float2 z0 = *reinterpret_cast<const float2*>(&z[(size_t)e0.x * 128 + c]);
        ax += z0.x * a0; ay += z0.y * a0; da += a0;
    }

    float inv = 1.f / (da + db + 1e-6f);
    float2 zv = *reinterpret_cast<const float2*>(&z[(size_t)n * 128 + c]);
    float x0 = (ax + bx) * inv + zv.x;
    float x1 = (ay + by) * inv + zv.y;
    float s = x0 + x1;
    for (int off = 32; off; off >>= 1) s += __shfl_xor(s, off);
    float mu = s * (1.f / 128.f);
    float d0 = x0 - mu, d1 = x1 - mu;
    float q = d0 * d0 + d1 * d1;
    for (int off = 32; off; off >>= 1) q += __shfl_xor(q, off);
    float rstd = rsqrtf(q * (1.f / 128.f) + 1e-5f);
    float2 gg = *reinterpret_cast<const float2*>(&g[c]);
    float2 bb = *reinterpret_cast<const float2*>(&bparm[c]);
    float y0 = d0 * rstd * gg.x + bb.x;
    float y1 = d1 * rstd * gg.y + bb.y;
    y0 = y0 > 0.f ? y0 : expf(y0) - 1.f;
    y1 = y1 > 0.f ? y1 : expf(y1) - 1.f;
    *reinterpret_cast<float2*>(&out[(size_t)n * 128 + c]) = make_float2(y0, y1);
}

extern "C" void kernel_launch(void* const* d_in, const int* in_sizes, int n_in,
                              void* d_out, int out_size, void* d_ws, size_t ws_size,
                              hipStream_t stream) {
    const float* h   = (const float*)d_in[0];
    const int*   ei  = (const int*)d_in[1];
    const float* ef  = (const float*)d_in[2];
    const float* Ww  = (const float*)d_in[3];
    const float* Wb  = (const float*)d_in[4];
    const float* att = (const float*)d_in[5];
    const float* lng = (const float*)d_in[6];
    const float* lnb = (const float*)d_in[7];
    float* out = (float*)d_out;

    const int N = in_sizes[0] / 128;   // 50000
    const int E = in_sizes[1] / 2;     // 800000
    const int* src = ei;
    const int* dst = ei + E;
    const int nb = (N + CHUNK - 1) / CHUNK;   // 49 (<=64 required)

    char* ws = (char*)d_ws;
    float* z      = (float*)ws; ws += (size_t)N * 128 * 4;
    float* s_src  = (float*)ws; ws += (size_t)N * 4 * 4;
    float* s_dst  = (float*)ws; ws += (size_t)N * 4 * 4;
    int*   counts = (int*)ws;   ws += (size_t)N * 4;
    int*   offs   = (int*)ws;   ws += (size_t)N * 4;
    int*   cursor = (int*)ws;   ws += (size_t)N * 4;
    int*   bsum   = (int*)ws;   ws += (size_t)64 * 4;
    int*   bscan  = (int*)ws;   ws += (size_t)64 * 4;
    int2*  es     = (int2*)ws;  ws += (size_t)E * 8;

    hipMemsetAsync(counts, 0, (size_t)N * 4, stream);

    dim3 gGemm((N + 31) / 32, 2);
    k_gemm<<<gGemm, 256, 0, stream>>>(h, Ww, Wb, z, N);
    k_hist<<<(E + 255) / 256, 256, 0, stream>>>(dst, counts, E);
    k_scores<<<(N * 4 + 255) / 256, 256, 0, stream>>>(z, att, s_src, s_dst, N);
    k_scan_block<<<nb, 256, 0, stream>>>(counts, offs, bsum, N);
    k_scan_top<<<1, 64, 0, stream>>>(bsum, bscan, nb);
    k_addoff<<<(N + 255) / 256, 256, 0, stream>>>(offs, cursor, bscan, N);
    k_scatter<<<(E + 255) / 256, 256, 0, stream>>>(src, dst, ef, cursor, es, E);
    k_agg_final<<<(N + 3) / 4, 256, 0, stream>>>(offs, counts, es, s_src, s_dst, att, z, lng, lnb, out, N);
}